// Round 1
// baseline (1372.713 us; speedup 1.0000x reference)
//
#include <hip/hip_runtime.h>
#include <math.h>

#define LVL 16
#define FEAT 2
#define TBL (1u << 19)
#define PR1 2654435761u
#define PR2 805459861u

struct EncParams {
    float resf[LVL];     // (float)res
    float resm1[LVL];    // (float)(res-1)
    unsigned s1[LVL];    // res+1
    unsigned s2[LVL];    // (res+1)^2
    unsigned dense_mask; // bit l set -> dense indexing
};

// --- prep: weight-norm the two MLP layers into workspace -------------------
__global__ __launch_bounds__(256)
void prep_weights(const float* __restrict__ v1, const float* __restrict__ g1,
                  const float* __restrict__ v2, const float* __restrict__ g2,
                  float* __restrict__ ws)
{
    int t = threadIdx.x;
    if (t < 64) {
        float s = 0.f;
        for (int i = 0; i < 32; ++i) { float v = v1[t * 32 + i]; s += v * v; }
        float scale = g1[t] / sqrtf(s);
        for (int i = 0; i < 32; ++i) ws[t * 32 + i] = v1[t * 32 + i] * scale;
    } else if (t < 67) {
        int r = t - 64;
        float s = 0.f;
        for (int i = 0; i < 64; ++i) { float v = v2[r * 64 + i]; s += v * v; }
        float scale = g2[r] / sqrtf(s);
        for (int i = 0; i < 64; ++i) ws[2048 + r * 64 + i] = v2[r * 64 + i] * scale;
    }
}

// --- fused encode + MLP ----------------------------------------------------
__global__ __launch_bounds__(256)
void fused_ngp(const float* __restrict__ x, const float* __restrict__ tables,
               const float* __restrict__ w1, const float* __restrict__ b1,
               const float* __restrict__ w2, const float* __restrict__ b2,
               float* __restrict__ out, int N, EncParams ep)
{
    int i = blockIdx.x * 256 + threadIdx.x;
    if (i >= N) return;

    float xn0 = (x[3 * i + 0] + 1.0f) * 0.5f;
    float xn1 = (x[3 * i + 1] + 1.0f) * 0.5f;
    float xn2 = (x[3 * i + 2] + 1.0f) * 0.5f;

    float h[2 * LVL];

#pragma unroll
    for (int l = 0; l < LVL; ++l) {
        float rf = ep.resf[l];
        float p0 = xn0 * rf, p1 = xn1 * rf, p2 = xn2 * rf;
        float pf0 = fminf(floorf(p0), ep.resm1[l]);
        float pf1 = fminf(floorf(p1), ep.resm1[l]);
        float pf2 = fminf(floorf(p2), ep.resm1[l]);
        float fr0 = p0 - pf0, fr1 = p1 - pf1, fr2 = p2 - pf2;
        unsigned c0 = (unsigned)pf0, c1 = (unsigned)pf1, c2 = (unsigned)pf2;

        const float2* tb = (const float2*)tables + (size_t)l * TBL;

        float acc0 = 0.f, acc1 = 0.f;
        if ((ep.dense_mask >> l) & 1u) {
            unsigned s1 = ep.s1[l], s2 = ep.s2[l];
            unsigned b = c0 + c1 * s1 + c2 * s2;
#pragma unroll
            for (int ox = 0; ox < 2; ++ox) {
#pragma unroll
                for (int oy = 0; oy < 2; ++oy) {
#pragma unroll
                    for (int oz = 0; oz < 2; ++oz) {
                        unsigned id = b + (unsigned)ox + (oy ? s1 : 0u) + (oz ? s2 : 0u);
                        float2 v = tb[id];
                        float w = (ox ? fr0 : 1.f - fr0) *
                                  (oy ? fr1 : 1.f - fr1) *
                                  (oz ? fr2 : 1.f - fr2);
                        acc0 = fmaf(w, v.x, acc0);
                        acc1 = fmaf(w, v.y, acc1);
                    }
                }
            }
        } else {
            unsigned hx0 = c0, hx1 = c0 + 1u;
            unsigned hy0 = c1 * PR1, hy1 = hy0 + PR1;
            unsigned hz0 = c2 * PR2, hz1 = hz0 + PR2;
#pragma unroll
            for (int ox = 0; ox < 2; ++ox) {
#pragma unroll
                for (int oy = 0; oy < 2; ++oy) {
#pragma unroll
                    for (int oz = 0; oz < 2; ++oz) {
                        unsigned id = ((ox ? hx1 : hx0) ^ (oy ? hy1 : hy0) ^ (oz ? hz1 : hz0)) & (TBL - 1u);
                        float2 v = tb[id];
                        float w = (ox ? fr0 : 1.f - fr0) *
                                  (oy ? fr1 : 1.f - fr1) *
                                  (oz ? fr2 : 1.f - fr2);
                        acc0 = fmaf(w, v.x, acc0);
                        acc1 = fmaf(w, v.y, acc1);
                    }
                }
            }
        }
        h[2 * l + 0] = acc0;
        h[2 * l + 1] = acc1;
    }

    // MLP: 32 -> 64 (relu) -> 3 (tanh). Weights are wave-uniform -> s_load path.
    float r0 = b2[0], r1 = b2[1], r2 = b2[2];
    for (int o = 0; o < 64; ++o) {
        float a = b1[o];
#pragma unroll
        for (int k = 0; k < 32; ++k) a = fmaf(h[k], w1[o * 32 + k], a);
        a = fmaxf(a, 0.f);
        r0 = fmaf(a, w2[0 * 64 + o], r0);
        r1 = fmaf(a, w2[1 * 64 + o], r1);
        r2 = fmaf(a, w2[2 * 64 + o], r2);
    }
    out[3 * i + 0] = tanhf(r0);
    out[3 * i + 1] = tanhf(r1);
    out[3 * i + 2] = tanhf(r2);
}

extern "C" void kernel_launch(void* const* d_in, const int* in_sizes, int n_in,
                              void* d_out, int out_size, void* d_ws, size_t ws_size,
                              hipStream_t stream)
{
    const float* x      = (const float*)d_in[0];
    const float* tables = (const float*)d_in[1];
    const float* v1     = (const float*)d_in[2];
    const float* g1     = (const float*)d_in[3];
    const float* b1     = (const float*)d_in[4];
    const float* v2     = (const float*)d_in[5];
    const float* g2     = (const float*)d_in[6];
    const float* b2     = (const float*)d_in[7];
    float* out = (float*)d_out;
    float* ws  = (float*)d_ws;
    int N = in_sizes[0] / 3;

    // Replicate the reference's per-level resolution computation with the
    // same double-precision libm sequence (exp/log/pow/floor) so the floor
    // at the exact power-of-two levels matches bit-for-bit.
    EncParams ep;
    double Bd = exp(log(512.0 / 16.0) / (double)(LVL - 1));
    unsigned dm = 0;
    for (int l = 0; l < LVL; ++l) {
        int res = (int)floor(16.0 * pow(Bd, (double)l));
        ep.resf[l]  = (float)res;
        ep.resm1[l] = (float)(res - 1);
        long long rp1 = (long long)res + 1;
        if (rp1 * rp1 * rp1 <= (long long)TBL) dm |= (1u << l);
        ep.s1[l] = (unsigned)(res + 1);
        ep.s2[l] = (unsigned)((res + 1) * (res + 1));
    }
    ep.dense_mask = dm;

    prep_weights<<<1, 256, 0, stream>>>(v1, g1, v2, g2, ws);
    fused_ngp<<<(N + 255) / 256, 256, 0, stream>>>(x, tables, ws, b1, ws + 2048, b2, out, N, ep);
}

// Round 2
// 1000.293 us; speedup vs baseline: 1.3723x; 1.3723x over previous
//
#include <hip/hip_runtime.h>
#include <math.h>

#define LVL 16
#define TBL (1u << 19)
#define PR1 2654435761u
#define PR2 805459861u
#define NDENSE 7
#define NHASH 9

// ---------------- params ----------------------------------------------------
struct EncParams {              // fallback (all 16 levels)
    float resf[LVL];
    float resm1[LVL];
    unsigned s1[LVL];
    unsigned s2[LVL];
    unsigned dense_mask;
};

struct DenseParams {            // fast path, levels 0..6
    float resf[NDENSE];
    float resm1[NDENSE];
    unsigned s1[NDENSE];
    unsigned s2[NDENSE];
};

// bf16 round-to-nearest-even
static __device__ __forceinline__ unsigned f2bf(float f) {
    unsigned u = __float_as_uint(f);
    u += 0x7FFFu + ((u >> 16) & 1u);
    return u >> 16;
}
static __device__ __forceinline__ float bf_lo(unsigned p) { return __uint_as_float(p << 16); }
static __device__ __forceinline__ float bf_hi(unsigned p) { return __uint_as_float(p & 0xFFFF0000u); }

// ---------------- prep: weight-norm MLP weights into ws ---------------------
__global__ __launch_bounds__(256)
void prep_weights(const float* __restrict__ v1, const float* __restrict__ g1,
                  const float* __restrict__ v2, const float* __restrict__ g2,
                  float* __restrict__ ws)
{
    int t = threadIdx.x;
    if (t < 64) {
        float s = 0.f;
        for (int i = 0; i < 32; ++i) { float v = v1[t * 32 + i]; s += v * v; }
        float scale = g1[t] / sqrtf(s);
        for (int i = 0; i < 32; ++i) ws[t * 32 + i] = v1[t * 32 + i] * scale;
    } else if (t < 67) {
        int r = t - 64;
        float s = 0.f;
        for (int i = 0; i < 64; ++i) { float v = v2[r * 64 + i]; s += v * v; }
        float scale = g2[r] / sqrtf(s);
        for (int i = 0; i < 64; ++i) ws[2048 + r * 64 + i] = v2[r * 64 + i] * scale;
    }
}

// ---------------- convert tables fp32 -> packed bf16x2 ----------------------
// one thread handles 2 table entries (float4 in -> uint2 out)
__global__ __launch_bounds__(256)
void convert_tables(const float4* __restrict__ src, uint2* __restrict__ dst, int npairs)
{
    int j = blockIdx.x * 256 + threadIdx.x;
    if (j >= npairs) return;
    float4 v = src[j];
    uint2 o;
    o.x = (f2bf(v.y) << 16) | f2bf(v.x);
    o.y = (f2bf(v.w) << 16) | f2bf(v.z);
    dst[j] = o;
}

// ---------------- per-hash-level encode (table L2-resident) -----------------
__global__ __launch_bounds__(256)
void encode_hash_level(const float* __restrict__ x, const unsigned* __restrict__ tb,
                       unsigned* __restrict__ hout, int N, float rf, float rm1)
{
    int i = blockIdx.x * 256 + threadIdx.x;
    if (i >= N) return;

    float xn0 = (x[3 * i + 0] + 1.0f) * 0.5f;
    float xn1 = (x[3 * i + 1] + 1.0f) * 0.5f;
    float xn2 = (x[3 * i + 2] + 1.0f) * 0.5f;

    float p0 = xn0 * rf, p1 = xn1 * rf, p2 = xn2 * rf;
    float pf0 = fminf(floorf(p0), rm1);
    float pf1 = fminf(floorf(p1), rm1);
    float pf2 = fminf(floorf(p2), rm1);
    float fr0 = p0 - pf0, fr1 = p1 - pf1, fr2 = p2 - pf2;
    unsigned c0 = (unsigned)pf0, c1 = (unsigned)pf1, c2 = (unsigned)pf2;

    unsigned hx0 = c0, hx1 = c0 + 1u;
    unsigned hy0 = c1 * PR1, hy1 = hy0 + PR1;
    unsigned hz0 = c2 * PR2, hz1 = hz0 + PR2;

    unsigned v[8];
#pragma unroll
    for (int c = 0; c < 8; ++c) {
        unsigned hx = (c & 4) ? hx1 : hx0;
        unsigned hy = (c & 2) ? hy1 : hy0;
        unsigned hz = (c & 1) ? hz1 : hz0;
        v[c] = tb[(hx ^ hy ^ hz) & (TBL - 1u)];
    }

    float acc0 = 0.f, acc1 = 0.f;
#pragma unroll
    for (int c = 0; c < 8; ++c) {
        float w = ((c & 4) ? fr0 : 1.f - fr0) *
                  ((c & 2) ? fr1 : 1.f - fr1) *
                  ((c & 1) ? fr2 : 1.f - fr2);
        acc0 = fmaf(w, bf_lo(v[c]), acc0);
        acc1 = fmaf(w, bf_hi(v[c]), acc1);
    }
    hout[i] = (f2bf(acc1) << 16) | f2bf(acc0);
}

// ---------------- final: dense levels + gather h + MLP ----------------------
__global__ __launch_bounds__(256)
void final_mlp(const float* __restrict__ x, const unsigned* __restrict__ tb,
               const unsigned* __restrict__ hbuf,
               const float* __restrict__ w1, const float* __restrict__ b1,
               const float* __restrict__ w2, const float* __restrict__ b2,
               float* __restrict__ out, int N, DenseParams dp)
{
    int i = blockIdx.x * 256 + threadIdx.x;
    if (i >= N) return;

    float xn0 = (x[3 * i + 0] + 1.0f) * 0.5f;
    float xn1 = (x[3 * i + 1] + 1.0f) * 0.5f;
    float xn2 = (x[3 * i + 2] + 1.0f) * 0.5f;

    float h[2 * LVL];

#pragma unroll
    for (int l = 0; l < NDENSE; ++l) {
        float rf = dp.resf[l];
        float p0 = xn0 * rf, p1 = xn1 * rf, p2 = xn2 * rf;
        float pf0 = fminf(floorf(p0), dp.resm1[l]);
        float pf1 = fminf(floorf(p1), dp.resm1[l]);
        float pf2 = fminf(floorf(p2), dp.resm1[l]);
        float fr0 = p0 - pf0, fr1 = p1 - pf1, fr2 = p2 - pf2;
        unsigned c0 = (unsigned)pf0, c1 = (unsigned)pf1, c2 = (unsigned)pf2;
        unsigned s1 = dp.s1[l], s2 = dp.s2[l];
        unsigned b = c0 + c1 * s1 + c2 * s2;
        const unsigned* t = tb + (size_t)l * TBL;

        float acc0 = 0.f, acc1 = 0.f;
#pragma unroll
        for (int c = 0; c < 8; ++c) {
            unsigned id = b + ((c & 4) ? 1u : 0u) + ((c & 2) ? s1 : 0u) + ((c & 1) ? s2 : 0u);
            unsigned p = t[id];
            float w = ((c & 4) ? fr0 : 1.f - fr0) *
                      ((c & 2) ? fr1 : 1.f - fr1) *
                      ((c & 1) ? fr2 : 1.f - fr2);
            acc0 = fmaf(w, bf_lo(p), acc0);
            acc1 = fmaf(w, bf_hi(p), acc1);
        }
        h[2 * l + 0] = acc0;
        h[2 * l + 1] = acc1;
    }

#pragma unroll
    for (int l = 0; l < NHASH; ++l) {
        unsigned p = hbuf[(size_t)l * N + i];
        h[2 * (NDENSE + l) + 0] = bf_lo(p);
        h[2 * (NDENSE + l) + 1] = bf_hi(p);
    }

    // MLP: 32 -> 64 relu -> 3 tanh (weights wave-uniform -> SGPR operands)
    float r0 = b2[0], r1 = b2[1], r2 = b2[2];
    for (int o = 0; o < 64; ++o) {
        float a = b1[o];
#pragma unroll
        for (int k = 0; k < 32; ++k) a = fmaf(h[k], w1[o * 32 + k], a);
        a = fmaxf(a, 0.f);
        r0 = fmaf(a, w2[0 * 64 + o], r0);
        r1 = fmaf(a, w2[1 * 64 + o], r1);
        r2 = fmaf(a, w2[2 * 64 + o], r2);
    }
    out[3 * i + 0] = tanhf(r0);
    out[3 * i + 1] = tanhf(r1);
    out[3 * i + 2] = tanhf(r2);
}

// ---------------- fallback: round-1 fused kernel (proven correct) -----------
__global__ __launch_bounds__(256)
void fused_ngp(const float* __restrict__ x, const float* __restrict__ tables,
               const float* __restrict__ w1, const float* __restrict__ b1,
               const float* __restrict__ w2, const float* __restrict__ b2,
               float* __restrict__ out, int N, EncParams ep)
{
    int i = blockIdx.x * 256 + threadIdx.x;
    if (i >= N) return;

    float xn0 = (x[3 * i + 0] + 1.0f) * 0.5f;
    float xn1 = (x[3 * i + 1] + 1.0f) * 0.5f;
    float xn2 = (x[3 * i + 2] + 1.0f) * 0.5f;

    float h[2 * LVL];

#pragma unroll
    for (int l = 0; l < LVL; ++l) {
        float rf = ep.resf[l];
        float p0 = xn0 * rf, p1 = xn1 * rf, p2 = xn2 * rf;
        float pf0 = fminf(floorf(p0), ep.resm1[l]);
        float pf1 = fminf(floorf(p1), ep.resm1[l]);
        float pf2 = fminf(floorf(p2), ep.resm1[l]);
        float fr0 = p0 - pf0, fr1 = p1 - pf1, fr2 = p2 - pf2;
        unsigned c0 = (unsigned)pf0, c1 = (unsigned)pf1, c2 = (unsigned)pf2;
        const float2* tb = (const float2*)tables + (size_t)l * TBL;

        float acc0 = 0.f, acc1 = 0.f;
        if ((ep.dense_mask >> l) & 1u) {
            unsigned s1 = ep.s1[l], s2 = ep.s2[l];
            unsigned b = c0 + c1 * s1 + c2 * s2;
#pragma unroll
            for (int c = 0; c < 8; ++c) {
                unsigned id = b + ((c & 4) ? 1u : 0u) + ((c & 2) ? s1 : 0u) + ((c & 1) ? s2 : 0u);
                float2 v = tb[id];
                float w = ((c & 4) ? fr0 : 1.f - fr0) *
                          ((c & 2) ? fr1 : 1.f - fr1) *
                          ((c & 1) ? fr2 : 1.f - fr2);
                acc0 = fmaf(w, v.x, acc0);
                acc1 = fmaf(w, v.y, acc1);
            }
        } else {
            unsigned hx0 = c0, hx1 = c0 + 1u;
            unsigned hy0 = c1 * PR1, hy1 = hy0 + PR1;
            unsigned hz0 = c2 * PR2, hz1 = hz0 + PR2;
#pragma unroll
            for (int c = 0; c < 8; ++c) {
                unsigned hx = (c & 4) ? hx1 : hx0;
                unsigned hy = (c & 2) ? hy1 : hy0;
                unsigned hz = (c & 1) ? hz1 : hz0;
                float2 v = tb[(hx ^ hy ^ hz) & (TBL - 1u)];
                float w = ((c & 4) ? fr0 : 1.f - fr0) *
                          ((c & 2) ? fr1 : 1.f - fr1) *
                          ((c & 1) ? fr2 : 1.f - fr2);
                acc0 = fmaf(w, v.x, acc0);
                acc1 = fmaf(w, v.y, acc1);
            }
        }
        h[2 * l + 0] = acc0;
        h[2 * l + 1] = acc1;
    }

    float r0 = b2[0], r1 = b2[1], r2 = b2[2];
    for (int o = 0; o < 64; ++o) {
        float a = b1[o];
#pragma unroll
        for (int k = 0; k < 32; ++k) a = fmaf(h[k], w1[o * 32 + k], a);
        a = fmaxf(a, 0.f);
        r0 = fmaf(a, w2[0 * 64 + o], r0);
        r1 = fmaf(a, w2[1 * 64 + o], r1);
        r2 = fmaf(a, w2[2 * 64 + o], r2);
    }
    out[3 * i + 0] = tanhf(r0);
    out[3 * i + 1] = tanhf(r1);
    out[3 * i + 2] = tanhf(r2);
}

// ---------------------------------------------------------------------------
extern "C" void kernel_launch(void* const* d_in, const int* in_sizes, int n_in,
                              void* d_out, int out_size, void* d_ws, size_t ws_size,
                              hipStream_t stream)
{
    const float* x      = (const float*)d_in[0];
    const float* tables = (const float*)d_in[1];
    const float* v1     = (const float*)d_in[2];
    const float* g1     = (const float*)d_in[3];
    const float* b1     = (const float*)d_in[4];
    const float* v2     = (const float*)d_in[5];
    const float* g2     = (const float*)d_in[6];
    const float* b2     = (const float*)d_in[7];
    float* out = (float*)d_out;
    float* ws  = (float*)d_ws;
    int N = in_sizes[0] / 3;
    int grid = (N + 255) / 256;

    // Replicate reference's double-precision level math exactly.
    EncParams ep;
    double Bd = exp(log(512.0 / 16.0) / (double)(LVL - 1));
    unsigned dm = 0;
    for (int l = 0; l < LVL; ++l) {
        int res = (int)floor(16.0 * pow(Bd, (double)l));
        ep.resf[l]  = (float)res;
        ep.resm1[l] = (float)(res - 1);
        long long rp1 = (long long)res + 1;
        if (rp1 * rp1 * rp1 <= (long long)TBL) dm |= (1u << l);
        ep.s1[l] = (unsigned)(res + 1);
        ep.s2[l] = (unsigned)((res + 1) * (res + 1));
    }
    ep.dense_mask = dm;

    prep_weights<<<1, 256, 0, stream>>>(v1, g1, v2, g2, ws);

    // workspace layout: [0,16KB) weights | [16KB, +32MB) bf16 tables | h buffer
    size_t tb_off_bytes = 16384;
    size_t h_off_bytes  = tb_off_bytes + (size_t)LVL * TBL * 4;
    size_t need = h_off_bytes + (size_t)NHASH * (size_t)N * 4;

    bool fast = (ws_size >= need) && (dm == 0x7Fu);
    if (fast) {
        unsigned* tb   = (unsigned*)((char*)d_ws + tb_off_bytes);
        unsigned* hbuf = (unsigned*)((char*)d_ws + h_off_bytes);

        int npairs = (int)((size_t)LVL * TBL / 2);   // 2 entries per thread
        convert_tables<<<(npairs + 255) / 256, 256, 0, stream>>>(
            (const float4*)tables, (uint2*)tb, npairs);

        for (int l = 0; l < NHASH; ++l) {
            int gl = NDENSE + l;
            encode_hash_level<<<grid, 256, 0, stream>>>(
                x, tb + (size_t)gl * TBL, hbuf + (size_t)l * N, N,
                ep.resf[gl], ep.resm1[gl]);
        }

        DenseParams dp;
        for (int l = 0; l < NDENSE; ++l) {
            dp.resf[l] = ep.resf[l]; dp.resm1[l] = ep.resm1[l];
            dp.s1[l] = ep.s1[l];     dp.s2[l] = ep.s2[l];
        }
        final_mlp<<<grid, 256, 0, stream>>>(x, tb, hbuf, ws, b1, ws + 2048, b2, out, N, dp);
    } else {
        fused_ngp<<<grid, 256, 0, stream>>>(x, tables, ws, b1, ws + 2048, b2, out, N, ep);
    }
}

// Round 3
// 982.781 us; speedup vs baseline: 1.3968x; 1.0178x over previous
//
#include <hip/hip_runtime.h>
#include <math.h>

#define LVL 16
#define TBL (1u << 19)
#define PR1 2654435761u
#define PR2 805459861u
#define NDENSE 7
#define NHASH 9

// ---------------- params ----------------------------------------------------
struct EncParams {              // fallback (all 16 levels)
    float resf[LVL];
    float resm1[LVL];
    unsigned s1[LVL];
    unsigned s2[LVL];
    unsigned dense_mask;
};

struct DenseParams {            // fast path, levels 0..6
    float resf[NDENSE];
    float resm1[NDENSE];
    unsigned s1[NDENSE];
    unsigned s2[NDENSE];
};

// bf16 round-to-nearest-even
static __device__ __forceinline__ unsigned f2bf(float f) {
    unsigned u = __float_as_uint(f);
    u += 0x7FFFu + ((u >> 16) & 1u);
    return u >> 16;
}
static __device__ __forceinline__ float bf_lo(unsigned p) { return __uint_as_float(p << 16); }
static __device__ __forceinline__ float bf_hi(unsigned p) { return __uint_as_float(p & 0xFFFF0000u); }

static __device__ __forceinline__ float fast_tanh(float v) {
    v = fminf(fmaxf(v, -10.f), 10.f);
    float e = __expf(2.0f * v);
    return __fdividef(e - 1.0f, e + 1.0f);
}

// ---------------- prep: weight-norm MLP weights into ws ---------------------
__global__ __launch_bounds__(256)
void prep_weights(const float* __restrict__ v1, const float* __restrict__ g1,
                  const float* __restrict__ v2, const float* __restrict__ g2,
                  float* __restrict__ ws)
{
    int t = threadIdx.x;
    if (t < 64) {
        float s = 0.f;
        for (int i = 0; i < 32; ++i) { float v = v1[t * 32 + i]; s += v * v; }
        float scale = g1[t] / sqrtf(s);
        for (int i = 0; i < 32; ++i) ws[t * 32 + i] = v1[t * 32 + i] * scale;
    } else if (t < 67) {
        int r = t - 64;
        float s = 0.f;
        for (int i = 0; i < 64; ++i) { float v = v2[r * 64 + i]; s += v * v; }
        float scale = g2[r] / sqrtf(s);
        for (int i = 0; i < 64; ++i) ws[2048 + r * 64 + i] = v2[r * 64 + i] * scale;
    }
}

// ---------------- convert tables fp32 -> packed bf16x2 ----------------------
__global__ __launch_bounds__(256)
void convert_tables(const float4* __restrict__ src, uint2* __restrict__ dst, int npairs)
{
    int j = blockIdx.x * 256 + threadIdx.x;
    if (j >= npairs) return;
    float4 v = src[j];
    uint2 o;
    o.x = (f2bf(v.y) << 16) | f2bf(v.x);
    o.y = (f2bf(v.w) << 16) | f2bf(v.z);
    dst[j] = o;
}

// ---------------- per-hash-level encode: 2 points/thread --------------------
__global__ __launch_bounds__(256, 4)
void encode_hash_level2(const float* __restrict__ x, const unsigned* __restrict__ tb,
                        unsigned* __restrict__ hout, int N, float rf, float rm1)
{
    int j = blockIdx.x * 256 + threadIdx.x;
    int i0 = 2 * j;
    if (i0 + 1 >= N) {
        if (i0 >= N) return;
        // scalar tail (only hit if N odd)
        float xn0 = (x[3 * i0 + 0] + 1.0f) * 0.5f;
        float xn1 = (x[3 * i0 + 1] + 1.0f) * 0.5f;
        float xn2 = (x[3 * i0 + 2] + 1.0f) * 0.5f;
        float p0 = xn0 * rf, p1 = xn1 * rf, p2 = xn2 * rf;
        float pf0 = fminf(floorf(p0), rm1), pf1 = fminf(floorf(p1), rm1), pf2 = fminf(floorf(p2), rm1);
        float fr0 = p0 - pf0, fr1 = p1 - pf1, fr2 = p2 - pf2;
        unsigned c0 = (unsigned)pf0, c1 = (unsigned)pf1, c2 = (unsigned)pf2;
        unsigned hx0 = c0, hx1 = c0 + 1u;
        unsigned hy0 = c1 * PR1, hy1 = hy0 + PR1;
        unsigned hz0 = c2 * PR2, hz1 = hz0 + PR2;
        float a0 = 0.f, a1 = 0.f;
#pragma unroll
        for (int c = 0; c < 8; ++c) {
            unsigned hx = (c & 4) ? hx1 : hx0;
            unsigned hy = (c & 2) ? hy1 : hy0;
            unsigned hz = (c & 1) ? hz1 : hz0;
            unsigned v = tb[(hx ^ hy ^ hz) & (TBL - 1u)];
            float w = ((c & 4) ? fr0 : 1.f - fr0) * ((c & 2) ? fr1 : 1.f - fr1) * ((c & 1) ? fr2 : 1.f - fr2);
            a0 = fmaf(w, bf_lo(v), a0);
            a1 = fmaf(w, bf_hi(v), a1);
        }
        hout[i0] = (f2bf(a1) << 16) | f2bf(a0);
        return;
    }

    const float2* xp = (const float2*)(x + 3 * i0);   // 8B-aligned (i0 even)
    float2 xa = xp[0], xb = xp[1], xc = xp[2];
    float A0 = (xa.x + 1.f) * 0.5f, A1 = (xa.y + 1.f) * 0.5f, A2 = (xb.x + 1.f) * 0.5f;
    float B0 = (xb.y + 1.f) * 0.5f, B1 = (xc.x + 1.f) * 0.5f, B2 = (xc.y + 1.f) * 0.5f;

    float pA0 = A0 * rf, pA1 = A1 * rf, pA2 = A2 * rf;
    float pB0 = B0 * rf, pB1 = B1 * rf, pB2 = B2 * rf;
    float fA0 = fminf(floorf(pA0), rm1), fA1 = fminf(floorf(pA1), rm1), fA2 = fminf(floorf(pA2), rm1);
    float fB0 = fminf(floorf(pB0), rm1), fB1 = fminf(floorf(pB1), rm1), fB2 = fminf(floorf(pB2), rm1);
    float rA0 = pA0 - fA0, rA1 = pA1 - fA1, rA2 = pA2 - fA2;
    float rB0 = pB0 - fB0, rB1 = pB1 - fB1, rB2 = pB2 - fB2;

    unsigned aX0 = (unsigned)fA0, aX1 = aX0 + 1u;
    unsigned aY0 = (unsigned)fA1 * PR1, aY1 = aY0 + PR1;
    unsigned aZ0 = (unsigned)fA2 * PR2, aZ1 = aZ0 + PR2;
    unsigned bX0 = (unsigned)fB0, bX1 = bX0 + 1u;
    unsigned bY0 = (unsigned)fB1 * PR1, bY1 = bY0 + PR1;
    unsigned bZ0 = (unsigned)fB2 * PR2, bZ1 = bZ0 + PR2;

    unsigned vA[8], vB[8];
#pragma unroll
    for (int c = 0; c < 8; ++c) {
        unsigned hx = (c & 4) ? aX1 : aX0;
        unsigned hy = (c & 2) ? aY1 : aY0;
        unsigned hz = (c & 1) ? aZ1 : aZ0;
        vA[c] = tb[(hx ^ hy ^ hz) & (TBL - 1u)];
    }
#pragma unroll
    for (int c = 0; c < 8; ++c) {
        unsigned hx = (c & 4) ? bX1 : bX0;
        unsigned hy = (c & 2) ? bY1 : bY0;
        unsigned hz = (c & 1) ? bZ1 : bZ0;
        vB[c] = tb[(hx ^ hy ^ hz) & (TBL - 1u)];
    }

    float a0 = 0.f, a1 = 0.f, b0 = 0.f, b1 = 0.f;
#pragma unroll
    for (int c = 0; c < 8; ++c) {
        float wA = ((c & 4) ? rA0 : 1.f - rA0) * ((c & 2) ? rA1 : 1.f - rA1) * ((c & 1) ? rA2 : 1.f - rA2);
        a0 = fmaf(wA, bf_lo(vA[c]), a0);
        a1 = fmaf(wA, bf_hi(vA[c]), a1);
        float wB = ((c & 4) ? rB0 : 1.f - rB0) * ((c & 2) ? rB1 : 1.f - rB1) * ((c & 1) ? rB2 : 1.f - rB2);
        b0 = fmaf(wB, bf_lo(vB[c]), b0);
        b1 = fmaf(wB, bf_hi(vB[c]), b1);
    }
    uint2 o;
    o.x = (f2bf(a1) << 16) | f2bf(a0);
    o.y = (f2bf(b1) << 16) | f2bf(b0);
    ((uint2*)hout)[j] = o;
}

// ---------------- final: dense levels + gather h + MLP ----------------------
__global__ __launch_bounds__(256, 4)
void final_mlp(const float* __restrict__ x, const unsigned* __restrict__ tb,
               const unsigned* __restrict__ hbuf,
               const float* __restrict__ w1, const float* __restrict__ b1,
               const float* __restrict__ w2, const float* __restrict__ b2,
               float* __restrict__ out, int N, DenseParams dp)
{
    int i = blockIdx.x * 256 + threadIdx.x;
    if (i >= N) return;

    // issue long-latency hbuf loads first (L3-resident, 9 in flight)
    unsigned hp[NHASH];
#pragma unroll
    for (int l = 0; l < NHASH; ++l) hp[l] = hbuf[(size_t)l * N + i];

    float xn0 = (x[3 * i + 0] + 1.0f) * 0.5f;
    float xn1 = (x[3 * i + 1] + 1.0f) * 0.5f;
    float xn2 = (x[3 * i + 2] + 1.0f) * 0.5f;

    // phase 1: compute all addresses, issue all 56 dense gathers
    unsigned cv[NDENSE][8];
    float fr[NDENSE][3];
#pragma unroll
    for (int l = 0; l < NDENSE; ++l) {
        float rf = dp.resf[l];
        float p0 = xn0 * rf, p1 = xn1 * rf, p2 = xn2 * rf;
        float pf0 = fminf(floorf(p0), dp.resm1[l]);
        float pf1 = fminf(floorf(p1), dp.resm1[l]);
        float pf2 = fminf(floorf(p2), dp.resm1[l]);
        fr[l][0] = p0 - pf0; fr[l][1] = p1 - pf1; fr[l][2] = p2 - pf2;
        unsigned s1 = dp.s1[l], s2 = dp.s2[l];
        unsigned b = (unsigned)pf0 + (unsigned)pf1 * s1 + (unsigned)pf2 * s2;
        const unsigned* t = tb + (size_t)l * TBL;
#pragma unroll
        for (int c = 0; c < 8; ++c) {
            unsigned id = b + ((c & 4) ? 1u : 0u) + ((c & 2) ? s1 : 0u) + ((c & 1) ? s2 : 0u);
            cv[l][c] = t[id];
        }
    }

    // phase 2: weights + accumulate features
    float h[2 * LVL];
#pragma unroll
    for (int l = 0; l < NDENSE; ++l) {
        float f0 = fr[l][0], f1 = fr[l][1], f2 = fr[l][2];
        float acc0 = 0.f, acc1 = 0.f;
#pragma unroll
        for (int c = 0; c < 8; ++c) {
            float w = ((c & 4) ? f0 : 1.f - f0) * ((c & 2) ? f1 : 1.f - f1) * ((c & 1) ? f2 : 1.f - f2);
            acc0 = fmaf(w, bf_lo(cv[l][c]), acc0);
            acc1 = fmaf(w, bf_hi(cv[l][c]), acc1);
        }
        h[2 * l + 0] = acc0;
        h[2 * l + 1] = acc1;
    }
#pragma unroll
    for (int l = 0; l < NHASH; ++l) {
        h[2 * (NDENSE + l) + 0] = bf_lo(hp[l]);
        h[2 * (NDENSE + l) + 1] = bf_hi(hp[l]);
    }

    // MLP: 32 -> 64 relu -> 3 tanh (weights wave-uniform -> scalar loads)
    float r0 = b2[0], r1 = b2[1], r2 = b2[2];
    for (int o = 0; o < 64; ++o) {
        float a = b1[o];
#pragma unroll
        for (int k = 0; k < 32; ++k) a = fmaf(h[k], w1[o * 32 + k], a);
        a = fmaxf(a, 0.f);
        r0 = fmaf(a, w2[0 * 64 + o], r0);
        r1 = fmaf(a, w2[1 * 64 + o], r1);
        r2 = fmaf(a, w2[2 * 64 + o], r2);
    }
    out[3 * i + 0] = fast_tanh(r0);
    out[3 * i + 1] = fast_tanh(r1);
    out[3 * i + 2] = fast_tanh(r2);
}

// ---------------- fallback: round-1 fused kernel (proven correct) -----------
__global__ __launch_bounds__(256)
void fused_ngp(const float* __restrict__ x, const float* __restrict__ tables,
               const float* __restrict__ w1, const float* __restrict__ b1,
               const float* __restrict__ w2, const float* __restrict__ b2,
               float* __restrict__ out, int N, EncParams ep)
{
    int i = blockIdx.x * 256 + threadIdx.x;
    if (i >= N) return;

    float xn0 = (x[3 * i + 0] + 1.0f) * 0.5f;
    float xn1 = (x[3 * i + 1] + 1.0f) * 0.5f;
    float xn2 = (x[3 * i + 2] + 1.0f) * 0.5f;

    float h[2 * LVL];

#pragma unroll
    for (int l = 0; l < LVL; ++l) {
        float rf = ep.resf[l];
        float p0 = xn0 * rf, p1 = xn1 * rf, p2 = xn2 * rf;
        float pf0 = fminf(floorf(p0), ep.resm1[l]);
        float pf1 = fminf(floorf(p1), ep.resm1[l]);
        float pf2 = fminf(floorf(p2), ep.resm1[l]);
        float fr0 = p0 - pf0, fr1 = p1 - pf1, fr2 = p2 - pf2;
        unsigned c0 = (unsigned)pf0, c1 = (unsigned)pf1, c2 = (unsigned)pf2;
        const float2* tb = (const float2*)tables + (size_t)l * TBL;

        float acc0 = 0.f, acc1 = 0.f;
        if ((ep.dense_mask >> l) & 1u) {
            unsigned s1 = ep.s1[l], s2 = ep.s2[l];
            unsigned b = c0 + c1 * s1 + c2 * s2;
#pragma unroll
            for (int c = 0; c < 8; ++c) {
                unsigned id = b + ((c & 4) ? 1u : 0u) + ((c & 2) ? s1 : 0u) + ((c & 1) ? s2 : 0u);
                float2 v = tb[id];
                float w = ((c & 4) ? fr0 : 1.f - fr0) * ((c & 2) ? fr1 : 1.f - fr1) * ((c & 1) ? fr2 : 1.f - fr2);
                acc0 = fmaf(w, v.x, acc0);
                acc1 = fmaf(w, v.y, acc1);
            }
        } else {
            unsigned hx0 = c0, hx1 = c0 + 1u;
            unsigned hy0 = c1 * PR1, hy1 = hy0 + PR1;
            unsigned hz0 = c2 * PR2, hz1 = hz0 + PR2;
#pragma unroll
            for (int c = 0; c < 8; ++c) {
                unsigned hx = (c & 4) ? hx1 : hx0;
                unsigned hy = (c & 2) ? hy1 : hy0;
                unsigned hz = (c & 1) ? hz1 : hz0;
                float2 v = tb[(hx ^ hy ^ hz) & (TBL - 1u)];
                float w = ((c & 4) ? fr0 : 1.f - fr0) * ((c & 2) ? fr1 : 1.f - fr1) * ((c & 1) ? fr2 : 1.f - fr2);
                acc0 = fmaf(w, v.x, acc0);
                acc1 = fmaf(w, v.y, acc1);
            }
        }
        h[2 * l + 0] = acc0;
        h[2 * l + 1] = acc1;
    }

    float r0 = b2[0], r1 = b2[1], r2 = b2[2];
    for (int o = 0; o < 64; ++o) {
        float a = b1[o];
#pragma unroll
        for (int k = 0; k < 32; ++k) a = fmaf(h[k], w1[o * 32 + k], a);
        a = fmaxf(a, 0.f);
        r0 = fmaf(a, w2[0 * 64 + o], r0);
        r1 = fmaf(a, w2[1 * 64 + o], r1);
        r2 = fmaf(a, w2[2 * 64 + o], r2);
    }
    out[3 * i + 0] = tanhf(r0);
    out[3 * i + 1] = tanhf(r1);
    out[3 * i + 2] = tanhf(r2);
}

// ---------------------------------------------------------------------------
extern "C" void kernel_launch(void* const* d_in, const int* in_sizes, int n_in,
                              void* d_out, int out_size, void* d_ws, size_t ws_size,
                              hipStream_t stream)
{
    const float* x      = (const float*)d_in[0];
    const float* tables = (const float*)d_in[1];
    const float* v1     = (const float*)d_in[2];
    const float* g1     = (const float*)d_in[3];
    const float* b1     = (const float*)d_in[4];
    const float* v2     = (const float*)d_in[5];
    const float* g2     = (const float*)d_in[6];
    const float* b2     = (const float*)d_in[7];
    float* out = (float*)d_out;
    float* ws  = (float*)d_ws;
    int N = in_sizes[0] / 3;
    int grid = (N + 255) / 256;

    // Replicate reference's double-precision level math exactly.
    EncParams ep;
    double Bd = exp(log(512.0 / 16.0) / (double)(LVL - 1));
    unsigned dm = 0;
    for (int l = 0; l < LVL; ++l) {
        int res = (int)floor(16.0 * pow(Bd, (double)l));
        ep.resf[l]  = (float)res;
        ep.resm1[l] = (float)(res - 1);
        long long rp1 = (long long)res + 1;
        if (rp1 * rp1 * rp1 <= (long long)TBL) dm |= (1u << l);
        ep.s1[l] = (unsigned)(res + 1);
        ep.s2[l] = (unsigned)((res + 1) * (res + 1));
    }
    ep.dense_mask = dm;

    prep_weights<<<1, 256, 0, stream>>>(v1, g1, v2, g2, ws);

    // workspace layout: [0,16KB) weights | [16KB, +32MB) bf16 tables | h buffer
    size_t tb_off_bytes = 16384;
    size_t h_off_bytes  = tb_off_bytes + (size_t)LVL * TBL * 4;
    size_t need = h_off_bytes + (size_t)NHASH * (size_t)N * 4;

    bool fast = (ws_size >= need) && (dm == 0x7Fu);
    if (fast) {
        unsigned* tb   = (unsigned*)((char*)d_ws + tb_off_bytes);
        unsigned* hbuf = (unsigned*)((char*)d_ws + h_off_bytes);

        int npairs = (int)((size_t)LVL * TBL / 2);
        convert_tables<<<(npairs + 255) / 256, 256, 0, stream>>>(
            (const float4*)tables, (uint2*)tb, npairs);

        int grid2 = ((N + 1) / 2 + 255) / 256;
        for (int l = 0; l < NHASH; ++l) {
            int gl = NDENSE + l;
            encode_hash_level2<<<grid2, 256, 0, stream>>>(
                x, tb + (size_t)gl * TBL, hbuf + (size_t)l * N, N,
                ep.resf[gl], ep.resm1[gl]);
        }

        DenseParams dp;
        for (int l = 0; l < NDENSE; ++l) {
            dp.resf[l] = ep.resf[l]; dp.resm1[l] = ep.resm1[l];
            dp.s1[l] = ep.s1[l];     dp.s2[l] = ep.s2[l];
        }
        final_mlp<<<grid, 256, 0, stream>>>(x, tb, hbuf, ws, b1, ws + 2048, b2, out, N, dp);
    } else {
        fused_ngp<<<grid, 256, 0, stream>>>(x, tables, ws, b1, ws + 2048, b2, out, N, ep);
    }
}